// Round 12
// baseline (342.590 us; speedup 1.0000x reference)
//
#include <hip/hip_runtime.h>
#include <hip/hip_bf16.h>
#include <math.h>

#define EPSN 1e-8f
#define MAXBUCK 512          // buckets of 128 nodes; requires N < 65536 (ushort col)

typedef __attribute__((ext_vector_type(8))) short short8;
typedef __attribute__((ext_vector_type(4))) float f32x4;

static __device__ __forceinline__ unsigned short f2bf(float f) {
    union { float f; unsigned int u; } v; v.f = f;
    unsigned int u = v.u;
    return (unsigned short)((u + 0x7fffu + ((u >> 16) & 1u)) >> 16);  // RNE
}
static __device__ __forceinline__ float bf2f(unsigned short h) {
    union { unsigned int u; float f; } v; v.u = ((unsigned int)h) << 16;
    return v.f;
}
static __device__ __forceinline__ unsigned int pk2(float a, float b) {
    return (((unsigned int)f2bf(b)) << 16) | (unsigned int)f2bf(a);
}

// ================= fused pre: bucket hist | weight prep | x->bf16 =================
__global__ void fused_pre(const int* __restrict__ dst, int* __restrict__ ghist, int E, int nbuck,
                          const float* __restrict__ Ws0, const float* __restrict__ Wn0,
                          const float* __restrict__ Ws1, const float* __restrict__ Wn1,
                          unsigned short* __restrict__ B0t, unsigned short* __restrict__ B1t,
                          float* __restrict__ bias,
                          const float* __restrict__ x, unsigned short* __restrict__ A0, int N,
                          int histB, int prepB) {
    int b = blockIdx.x;
    if (b < histB) {
        __shared__ int h[MAXBUCK];
        for (int i = threadIdx.x; i < MAXBUCK; i += 256) h[i] = 0;
        __syncthreads();
        int CH = (E + histB - 1) / histB;
        int lo = b * CH, hi = min(E, lo + CH);
        for (int e = lo + (int)threadIdx.x; e < hi; e += 256) atomicAdd(&h[dst[e] >> 7], 1);
        __syncthreads();
        for (int i = threadIdx.x; i < nbuck; i += 256) if (h[i]) atomicAdd(&ghist[i], h[i]);
        return;
    }
    if (b < histB + prepB) {
        int t = (b - histB) * 256 + threadIdx.x;
        if (t < 128 * 160) {
            int n = t / 160, k = t % 160;
            float v = 0.f;
            if (k < 64) v = Ws0[k * 128 + n];
            else if (k < 128) v = Wn0[(k - 64) * 128 + n];
            else if (k == 128) v = Ws0[64 * 128 + n];
            else if (k == 129) v = Wn0[64 * 128 + n];
            B0t[n * 160 + k] = f2bf(v);
        }
        int u = t - 128 * 160;
        if (u >= 0 && u < 32 * 128) {
            int c = u / 128, k = u % 128;
            float v = 0.f;
            if (c < 10) v = Ws1[k * 10 + c];
            else if (c < 20) v = Wn1[k * 10 + (c - 10)];
            B1t[c * 128 + k] = f2bf(v);
        }
        int w = t - 128 * 160 - 32 * 128;
        if (w >= 0 && w < 20) bias[w] = (w < 10) ? Ws1[128 * 10 + w] : Wn1[128 * 10 + (w - 10)];
        return;
    }
    int u = (b - histB - prepB) * 256 + threadIdx.x;   // u = n*8 + s
    if (u >= N * 8) return;
    int n = u >> 3, s = u & 7;
    const float4* xp = (const float4*)(x + (size_t)n * 64 + s * 8);
    float4 v0 = xp[0], v1 = xp[1];
    short8 r;
    r[0] = (short)f2bf(v0.x); r[1] = (short)f2bf(v0.y);
    r[2] = (short)f2bf(v0.z); r[3] = (short)f2bf(v0.w);
    r[4] = (short)f2bf(v1.x); r[5] = (short)f2bf(v1.y);
    r[6] = (short)f2bf(v1.z); r[7] = (short)f2bf(v1.w);
    *(short8*)(&A0[(size_t)n * 160 + s * 8]) = r;
}

// ================= bucket scan (1 block) =================
__global__ void bucket_scan(const int* __restrict__ ghist, int* __restrict__ boff,
                            int* __restrict__ bcur, int nbuck, int E,
                            int* __restrict__ row_ptr, int N) {
    __shared__ int bufa[MAXBUCK], bufb[MAXBUCK];
    int t = threadIdx.x;  // MAXBUCK threads
    int v = (t < nbuck) ? ghist[t] : 0;
    bufa[t] = v;
    __syncthreads();
    int* cur = bufa; int* nxt = bufb;
    for (int off = 1; off < MAXBUCK; off <<= 1) {
        int xv = cur[t];
        if (t >= off) xv += cur[t - off];
        nxt[t] = xv;
        __syncthreads();
        int* tmp = cur; cur = nxt; nxt = tmp;
    }
    int incl = cur[t];
    int excl = incl - v;
    if (t < nbuck) { boff[t] = excl; bcur[t] = excl; }
    if (t == nbuck - 1) boff[nbuck] = incl;   // == E
    if (t == 0) row_ptr[N] = E;
}

// ================= binned scatter of packed (local_dst<<16 | src) =================
__global__ void bucket_scatter(const int* __restrict__ src, const int* __restrict__ dst,
                               int* __restrict__ bcur, unsigned int* __restrict__ pairs,
                               int E) {
    __shared__ int h[MAXBUCK];
    __shared__ int bs[MAXBUCK];
    for (int i = threadIdx.x; i < MAXBUCK; i += 256) h[i] = 0;
    __syncthreads();
    int CH = (E + gridDim.x - 1) / gridDim.x;
    int lo = blockIdx.x * CH, hi = min(E, lo + CH);
    for (int e = lo + (int)threadIdx.x; e < hi; e += 256) atomicAdd(&h[dst[e] >> 7], 1);
    __syncthreads();
    for (int i = threadIdx.x; i < MAXBUCK; i += 256) {
        int c = h[i];
        bs[i] = c ? atomicAdd(&bcur[i], c) : 0;
        h[i] = 0;
    }
    __syncthreads();
    for (int e = lo + (int)threadIdx.x; e < hi; e += 256) {
        int d = dst[e];
        int b = d >> 7;
        int idx = atomicAdd(&h[b], 1);
        pairs[bs[b] + idx] = (((unsigned int)(d & 127)) << 16) | (unsigned int)src[e];
    }
}

// ================= per-bucket finalize -> row_ptr + ushort col =================
__global__ void csr_finalize(const unsigned int* __restrict__ pairs, const int* __restrict__ boff,
                             int* __restrict__ row_ptr, unsigned short* __restrict__ col,
                             int N) {
    __shared__ int lh[128], ls[128], lc[128];
    int b = blockIdx.x, t = threadIdx.x;  // 256 threads
    int lo = boff[b], hi = boff[b + 1];
    for (int i = t; i < 128; i += 256) lh[i] = 0;
    __syncthreads();
    for (int e = lo + t; e < hi; e += 256) atomicAdd(&lh[pairs[e] >> 16], 1);
    __syncthreads();
    if (t < 128) {
        int v = lh[t];
        int incl = v;
#pragma unroll
        for (int off = 1; off < 64; off <<= 1) {
            int y = __shfl_up(incl, off);
            if ((t & 63) >= off) incl += y;
        }
        ls[t] = incl;
    }
    __syncthreads();
    if (t < 128) {
        int v = lh[t];
        int excl = ls[t] - v + ((t >= 64) ? ls[63] : 0);
        int node = b * 128 + t;
        if (node < N) row_ptr[node] = lo + excl;
        lc[t] = excl;
    }
    __syncthreads();
    for (int e = lo + t; e < hi; e += 256) {
        unsigned int p = pairs[e];
        int ld = p >> 16;
        int idx = atomicAdd(&lc[ld], 1);
        col[lo + idx] = (unsigned short)(p & 0xFFFFu);
    }
}

// ================= agg0: wave-per-node gather-mean, 16-deep MLP (IDEMPOTENT) =================
__global__ void agg0_kernel(const int* __restrict__ row_ptr, const unsigned short* __restrict__ col,
                            unsigned short* __restrict__ A0, int N) {
    int n = (int)((blockIdx.x * blockDim.x + threadIdx.x) >> 6);
    if (n >= N) return;
    int lane = threadIdx.x & 63;
    int rs = row_ptr[n], re = row_ptr[n + 1];
    float acc = 0.f;
    for (int base = rs; base < re; base += 64) {
        int cnt = min(64, re - base);
        int e = 0;
        if (base + lane < re) e = (int)col[base + lane];
        int j = 0;
        for (; j + 16 <= cnt; j += 16) {
            float v[16];
#pragma unroll
            for (int i = 0; i < 16; ++i) {
                int s = __shfl(e, j + i);
                v[i] = bf2f(A0[(size_t)s * 160 + lane]);
            }
#pragma unroll
            for (int i = 0; i < 16; ++i) acc += v[i];
        }
        for (; j + 4 <= cnt; j += 4) {
            float v[4];
#pragma unroll
            for (int i = 0; i < 4; ++i) {
                int s = __shfl(e, j + i);
                v[i] = bf2f(A0[(size_t)s * 160 + lane]);
            }
#pragma unroll
            for (int i = 0; i < 4; ++i) acc += v[i];
        }
        for (; j < cnt; ++j) {
            int s = __shfl(e, j);
            acc += bf2f(A0[(size_t)s * 160 + lane]);
        }
    }
    float deg = (float)(re - rs);
    float scale = 1.0f / fmaxf(deg, 1.0f);
    unsigned short* row = A0 + (size_t)n * 160;
    row[64 + lane] = f2bf(acc * scale);                 // neigh cols 64..127
    if (lane == 0) *(unsigned int*)(&row[128]) = pk2(1.0f, deg * scale);  // (1.0, degscale)
    if (lane >= 1 && lane < 16) *(unsigned int*)(&row[128 + lane * 2]) = 0u;  // pad 130..159
}

// ================= GEMM0: h1 = relu(normalize(A0 @ B0)) =================
__global__ void __launch_bounds__(256)
gemm0_kernel(const unsigned short* __restrict__ A0, const unsigned short* __restrict__ B0t,
             unsigned short* __restrict__ h1, int N) {
    __shared__ unsigned short As[64 * 168];
    __shared__ unsigned short Bs[128 * 168];
    int t = threadIdx.x, blk = blockIdx.x;
    for (int i = t; i < 128 * 20; i += 256) {
        int r = i / 20, c = i % 20;
        *(uint4*)(&Bs[r * 168 + c * 8]) = *(const uint4*)(&B0t[r * 160 + c * 8]);
    }
    for (int i = t; i < 64 * 20; i += 256) {
        int r = i / 20, c = i % 20;
        int gr = blk * 64 + r;
        uint4 v = {0, 0, 0, 0};
        if (gr < N) v = *(const uint4*)(&A0[(size_t)gr * 160 + c * 8]);
        *(uint4*)(&As[r * 168 + c * 8]) = v;
    }
    __syncthreads();

    int wave = t >> 6, lane = t & 63;
    int lo = lane & 15, hi = lane >> 4;
    f32x4 acc[8];
#pragma unroll
    for (int f = 0; f < 8; ++f) acc[f] = (f32x4){0.f, 0.f, 0.f, 0.f};

#pragma unroll
    for (int ks = 0; ks < 5; ++ks) {
        short8 a = *(const short8*)(&As[(wave * 16 + lo) * 168 + ks * 32 + hi * 8]);
#pragma unroll
        for (int f = 0; f < 8; ++f) {
            short8 b = *(const short8*)(&Bs[(f * 16 + lo) * 168 + ks * 32 + hi * 8]);
            acc[f] = __builtin_amdgcn_mfma_f32_16x16x32_bf16(a, b, acc[f], 0, 0, 0);
        }
    }
#pragma unroll
    for (int j = 0; j < 4; ++j) {
        float s = 0.f;
#pragma unroll
        for (int f = 0; f < 8; ++f) s += acc[f][j] * acc[f][j];
#pragma unroll
        for (int m = 1; m < 16; m <<= 1) s += __shfl_xor(s, m);
        float inv = 1.0f / (sqrtf(s) + EPSN);
        int gr = blk * 64 + wave * 16 + hi * 4 + j;
        if (gr < N) {
#pragma unroll
            for (int f = 0; f < 8; ++f)
                h1[(size_t)gr * 128 + f * 16 + lo] = f2bf(fmaxf(acc[f][j] * inv, 0.f));
        }
    }
}

// ================= GEMM1: S[N][10] = h1@Ws1+b ; Qp[N][16] = [h1@Wn1+b | 0 pad] =================
__global__ void __launch_bounds__(256)
gemm1_kernel(const unsigned short* __restrict__ h1, const unsigned short* __restrict__ B1t,
             const float* __restrict__ bias, float* __restrict__ S, float* __restrict__ Qp, int N) {
    __shared__ unsigned short As[128 * 136];
    __shared__ unsigned short Bs[32 * 136];
    int t = threadIdx.x, blk = blockIdx.x;
    for (int i = t; i < 32 * 16; i += 256) {
        int r = i / 16, c = i % 16;
        *(uint4*)(&Bs[r * 136 + c * 8]) = *(const uint4*)(&B1t[r * 128 + c * 8]);
    }
    for (int i = t; i < 128 * 16; i += 256) {
        int r = i / 16, c = i % 16;
        int gr = blk * 128 + r;
        uint4 v = {0, 0, 0, 0};
        if (gr < N) v = *(const uint4*)(&h1[(size_t)gr * 128 + c * 8]);
        *(uint4*)(&As[r * 136 + c * 8]) = v;
    }
    __syncthreads();

    int wave = t >> 6, lane = t & 63, lo = lane & 15, hi = lane >> 4;
    f32x4 acc[2][2];
#pragma unroll
    for (int m = 0; m < 2; ++m) { acc[m][0] = (f32x4){0,0,0,0}; acc[m][1] = (f32x4){0,0,0,0}; }

#pragma unroll
    for (int ks = 0; ks < 4; ++ks) {
        short8 b0 = *(const short8*)(&Bs[lo * 136 + ks * 32 + hi * 8]);
        short8 b1 = *(const short8*)(&Bs[(16 + lo) * 136 + ks * 32 + hi * 8]);
#pragma unroll
        for (int m = 0; m < 2; ++m) {
            short8 a = *(const short8*)(&As[(wave * 32 + m * 16 + lo) * 136 + ks * 32 + hi * 8]);
            acc[m][0] = __builtin_amdgcn_mfma_f32_16x16x32_bf16(a, b0, acc[m][0], 0, 0, 0);
            acc[m][1] = __builtin_amdgcn_mfma_f32_16x16x32_bf16(a, b1, acc[m][1], 0, 0, 0);
        }
    }
#pragma unroll
    for (int m = 0; m < 2; ++m)
#pragma unroll
        for (int j = 0; j < 4; ++j) {
            int gr = blk * 128 + wave * 32 + m * 16 + hi * 4 + j;
            if (gr < N) {
                float v0 = acc[m][0][j] + bias[lo];
                if (lo < 10) S[(size_t)gr * 10 + lo] = v0;
                else         Qp[(size_t)gr * 16 + (lo - 10)] = v0;                          // cols 0..5
                if (lo < 4)       Qp[(size_t)gr * 16 + 6 + lo] = acc[m][1][j] + bias[16 + lo]; // 6..9
                else if (lo < 10) Qp[(size_t)gr * 16 + 6 + lo] = 0.f;                       // pad 10..15
            }
        }
}

// ================= final: thread-per-node; 4-edge unroll; log_softmax =================
__global__ void final_kernel(const float* __restrict__ S, const float* __restrict__ Qp,
                             const int* __restrict__ row_ptr, const unsigned short* __restrict__ col,
                             float* __restrict__ out, int N) {
    int n = blockIdx.x * blockDim.x + threadIdx.x;
    if (n >= N) return;
    int rs = row_ptr[n], re = row_ptr[n + 1];
    float q0 = 0.f, q1 = 0.f, q2 = 0.f, q3 = 0.f, q4 = 0.f;
    float q5 = 0.f, q6 = 0.f, q7 = 0.f, q8 = 0.f, q9 = 0.f;
    int e = rs;
    for (; e + 3 < re; e += 4) {
        float4 a[4], b[4]; float2 t2[4];
#pragma unroll
        for (int i = 0; i < 4; ++i) {
            int c = (int)col[e + i];
            const float4* r = (const float4*)(&Qp[(size_t)c * 16]);
            a[i] = r[0]; b[i] = r[1];
            t2[i] = *(const float2*)(&Qp[(size_t)c * 16 + 8]);
        }
#pragma unroll
        for (int i = 0; i < 4; ++i) {
            q0 += a[i].x; q1 += a[i].y; q2 += a[i].z; q3 += a[i].w;
            q4 += b[i].x; q5 += b[i].y; q6 += b[i].z; q7 += b[i].w;
            q8 += t2[i].x; q9 += t2[i].y;
        }
    }
    for (; e < re; ++e) {
        int c0 = (int)col[e];
        const float4* r0 = (const float4*)(&Qp[(size_t)c0 * 16]);
        float4 a0 = r0[0], b0 = r0[1];
        float2 t0 = *(const float2*)(&Qp[(size_t)c0 * 16 + 8]);
        q0 += a0.x; q1 += a0.y; q2 += a0.z; q3 += a0.w;
        q4 += b0.x; q5 += b0.y; q6 += b0.z; q7 += b0.w;
        q8 += t0.x; q9 += t0.y;
    }
    float deg = (float)(re - rs);
    float scale = 1.0f / fmaxf(deg, 1.0f);
    const float* Sr = &S[(size_t)n * 10];
    float p[10];
    p[0] = Sr[0] + q0 * scale; p[1] = Sr[1] + q1 * scale;
    p[2] = Sr[2] + q2 * scale; p[3] = Sr[3] + q3 * scale;
    p[4] = Sr[4] + q4 * scale; p[5] = Sr[5] + q5 * scale;
    p[6] = Sr[6] + q6 * scale; p[7] = Sr[7] + q7 * scale;
    p[8] = Sr[8] + q8 * scale; p[9] = Sr[9] + q9 * scale;
    float ss = 0.f;
#pragma unroll
    for (int j = 0; j < 10; ++j) ss = fmaf(p[j], p[j], ss);
    float inv = 1.0f / (sqrtf(ss) + EPSN);
    float m = -INFINITY;
#pragma unroll
    for (int j = 0; j < 10; ++j) { p[j] *= inv; m = fmaxf(m, p[j]); }
    float se = 0.f;
#pragma unroll
    for (int j = 0; j < 10; ++j) se += expf(p[j] - m);
    float ls = logf(se) + m;
#pragma unroll
    for (int j = 0; j < 10; ++j) out[(size_t)n * 10 + j] = p[j] - ls;
}

extern "C" void kernel_launch(void* const* d_in, const int* in_sizes, int n_in,
                              void* d_out, int out_size, void* d_ws, size_t ws_size,
                              hipStream_t stream) {
    const float* x   = (const float*)d_in[0];
    const int*   ei  = (const int*)d_in[1];
    const float* Ws0 = (const float*)d_in[2];
    const float* Wn0 = (const float*)d_in[3];
    const float* Ws1 = (const float*)d_in[4];
    const float* Wn1 = (const float*)d_in[5];

    int N = in_sizes[0] / 64;
    int E = in_sizes[1] / 2;
    const int* src = ei;
    const int* dst = ei + E;
    int nbuck = (N + 127) / 128;

    char* ws = (char*)d_ws;
    size_t off = 0;
    unsigned short* A0   = (unsigned short*)(ws + off); off += (size_t)N * 160 * 2;
    unsigned short* h1   = (unsigned short*)(ws + off); off += (size_t)N * 128 * 2;
    float*          S    = (float*)(ws + off);          off += (size_t)N * 10 * 4;
    float*          Qp   = (float*)(ws + off);          off += (size_t)N * 16 * 4;
    unsigned short* B0t  = (unsigned short*)(ws + off); off += 128 * 160 * 2;
    unsigned short* B1t  = (unsigned short*)(ws + off); off += 32 * 128 * 2;
    float*          bias = (float*)(ws + off);          off += 128;
    int*            rowp = (int*)(ws + off);            off += ((size_t)N + 4) * 4;
    unsigned short* colb = (unsigned short*)(ws + off); off += ((size_t)E + 8) * 2;
    unsigned int*   pairs= (unsigned int*)(ws + off);   off += (size_t)E * 4;
    int*            ghist= (int*)(ws + off);            off += MAXBUCK * 4;
    int*            boff = (int*)(ws + off);            off += (MAXBUCK + 1) * 4;
    int*            bcur = (int*)(ws + off);            off += MAXBUCK * 4;
    float* outp = (float*)d_out;

    int histB = 256;
    int prepB = (128 * 160 + 32 * 128 + 20 + 255) / 256;
    int xcvB  = (N * 8 + 255) / 256;

    hipMemsetAsync(ghist, 0, MAXBUCK * 4, stream);
    fused_pre<<<histB + prepB + xcvB, 256, 0, stream>>>(
        dst, ghist, E, nbuck, Ws0, Wn0, Ws1, Wn1, B0t, B1t, bias, x, A0, N, histB, prepB);
    bucket_scan   <<<1, MAXBUCK, 0, stream>>>(ghist, boff, bcur, nbuck, E, rowp, N);
    bucket_scatter<<<256, 256, 0, stream>>>(src, dst, bcur, pairs, E);
    csr_finalize  <<<nbuck, 256, 0, stream>>>(pairs, boff, rowp, colb, N);

    // MEASUREMENT: agg0 is idempotent; run 8x so t_agg0 = (dur_us - T_base)/7
    for (int rep = 0; rep < 8; ++rep)
        agg0_kernel <<<(N + 3) / 4, 256, 0, stream>>>(rowp, colb, A0, N);

    gemm0_kernel<<<(N + 63) / 64, 256, 0, stream>>>(A0, B0t, h1, N);
    gemm1_kernel<<<(N + 127) / 128, 256, 0, stream>>>(h1, B1t, bias, S, Qp, N);
    final_kernel<<<(N + 255) / 256, 256, 0, stream>>>(S, Qp, rowp, colb, outp, N);
}

// Round 14
// 188.667 us; speedup vs baseline: 1.8158x; 1.8158x over previous
//
#include <hip/hip_runtime.h>
#include <hip/hip_bf16.h>
#include <math.h>

#define EPSN 1e-8f
#define MAXBUCK 512          // buckets of 128 nodes; requires N < 65536 (ushort col)
#define HISTB 512            // hist/scatter grid (must match between fused_pre & bucket_scatter)

typedef __attribute__((ext_vector_type(8))) short short8;
typedef __attribute__((ext_vector_type(4))) float f32x4;

static __device__ __forceinline__ unsigned short f2bf(float f) {
    union { float f; unsigned int u; } v; v.f = f;
    unsigned int u = v.u;
    return (unsigned short)((u + 0x7fffu + ((u >> 16) & 1u)) >> 16);  // RNE
}
static __device__ __forceinline__ float bf2f(unsigned short h) {
    union { unsigned int u; float f; } v; v.u = ((unsigned int)h) << 16;
    return v.f;
}
static __device__ __forceinline__ unsigned int pk2(float a, float b) {
    return (((unsigned int)f2bf(b)) << 16) | (unsigned int)f2bf(a);
}

// ================= fused pre: bucket hist (-> ghist + phist) | weight prep | x->bf16 =================
__global__ void fused_pre(const int* __restrict__ dst, int* __restrict__ ghist,
                          int* __restrict__ phist, int E, int nbuck,
                          const float* __restrict__ Ws0, const float* __restrict__ Wn0,
                          const float* __restrict__ Ws1, const float* __restrict__ Wn1,
                          unsigned short* __restrict__ B0t, unsigned short* __restrict__ B1t,
                          float* __restrict__ bias,
                          const float* __restrict__ x, unsigned short* __restrict__ A0, int N,
                          int prepB) {
    int b = blockIdx.x;
    if (b < HISTB) {
        __shared__ int h[MAXBUCK];
        for (int i = threadIdx.x; i < MAXBUCK; i += 256) h[i] = 0;
        __syncthreads();
        int CH = (E + HISTB - 1) / HISTB;
        int lo = b * CH, hi = min(E, lo + CH);
        for (int e = lo + (int)threadIdx.x; e < hi; e += 256) atomicAdd(&h[dst[e] >> 7], 1);
        __syncthreads();
        for (int i = threadIdx.x; i < MAXBUCK; i += 256) {
            int c = h[i];
            phist[b * MAXBUCK + i] = c;                  // per-block counts for scatter
            if (c && i < nbuck) atomicAdd(&ghist[i], c);
        }
        return;
    }
    if (b < HISTB + prepB) {
        int t = (b - HISTB) * 256 + threadIdx.x;
        if (t < 128 * 160) {
            int n = t / 160, k = t % 160;
            float v = 0.f;
            if (k < 64) v = Ws0[k * 128 + n];
            else if (k < 128) v = Wn0[(k - 64) * 128 + n];
            else if (k == 128) v = Ws0[64 * 128 + n];
            else if (k == 129) v = Wn0[64 * 128 + n];
            B0t[n * 160 + k] = f2bf(v);
        }
        int u = t - 128 * 160;
        if (u >= 0 && u < 32 * 128) {
            int c = u / 128, k = u % 128;
            float v = 0.f;
            if (c < 10) v = Ws1[k * 10 + c];
            else if (c < 20) v = Wn1[k * 10 + (c - 10)];
            B1t[c * 128 + k] = f2bf(v);
        }
        int w = t - 128 * 160 - 32 * 128;
        if (w >= 0 && w < 20) bias[w] = (w < 10) ? Ws1[128 * 10 + w] : Wn1[128 * 10 + (w - 10)];
        return;
    }
    int u = (b - HISTB - prepB) * 256 + threadIdx.x;   // u = n*8 + s
    if (u >= N * 8) return;
    int n = u >> 3, s = u & 7;
    const float4* xp = (const float4*)(x + (size_t)n * 64 + s * 8);
    float4 v0 = xp[0], v1 = xp[1];
    short8 r;
    r[0] = (short)f2bf(v0.x); r[1] = (short)f2bf(v0.y);
    r[2] = (short)f2bf(v0.z); r[3] = (short)f2bf(v0.w);
    r[4] = (short)f2bf(v1.x); r[5] = (short)f2bf(v1.y);
    r[6] = (short)f2bf(v1.z); r[7] = (short)f2bf(v1.w);
    *(short8*)(&A0[(size_t)n * 160 + s * 8]) = r;
}

// ================= bucket scan (1 block) =================
__global__ void bucket_scan(const int* __restrict__ ghist, int* __restrict__ boff,
                            int* __restrict__ bcur, int nbuck, int E,
                            int* __restrict__ row_ptr, int N) {
    __shared__ int bufa[MAXBUCK], bufb[MAXBUCK];
    int t = threadIdx.x;  // MAXBUCK threads
    int v = (t < nbuck) ? ghist[t] : 0;
    bufa[t] = v;
    __syncthreads();
    int* cur = bufa; int* nxt = bufb;
    for (int off = 1; off < MAXBUCK; off <<= 1) {
        int xv = cur[t];
        if (t >= off) xv += cur[t - off];
        nxt[t] = xv;
        __syncthreads();
        int* tmp = cur; cur = nxt; nxt = tmp;
    }
    int incl = cur[t];
    int excl = incl - v;
    if (t < nbuck) { boff[t] = excl; bcur[t] = excl; }
    if (t == nbuck - 1) boff[nbuck] = incl;   // == E
    if (t == 0) row_ptr[N] = E;
}

// ================= binned scatter (uses precomputed per-block hist) =================
__global__ void bucket_scatter(const int* __restrict__ src, const int* __restrict__ dst,
                               const int* __restrict__ phist,
                               int* __restrict__ bcur, unsigned int* __restrict__ pairs,
                               int E) {
    __shared__ int h[MAXBUCK];
    __shared__ int bs[MAXBUCK];
    int b = blockIdx.x;
    for (int i = threadIdx.x; i < MAXBUCK; i += 256) {
        int c = phist[b * MAXBUCK + i];
        bs[i] = c ? atomicAdd(&bcur[i], c) : 0;
        h[i] = 0;
    }
    __syncthreads();
    int CH = (E + HISTB - 1) / HISTB;
    int lo = b * CH, hi = min(E, lo + CH);
    for (int e = lo + (int)threadIdx.x; e < hi; e += 256) {
        int d = dst[e];
        int bkt = d >> 7;
        int idx = atomicAdd(&h[bkt], 1);
        pairs[bs[bkt] + idx] = (((unsigned int)(d & 127)) << 16) | (unsigned int)src[e];
    }
}

// ================= per-bucket finalize -> row_ptr + ushort col =================
__global__ void csr_finalize(const unsigned int* __restrict__ pairs, const int* __restrict__ boff,
                             int* __restrict__ row_ptr, unsigned short* __restrict__ col,
                             int N) {
    __shared__ int lh[128], ls[128], lc[128];
    int b = blockIdx.x, t = threadIdx.x;  // 256 threads
    int lo = boff[b], hi = boff[b + 1];
    for (int i = t; i < 128; i += 256) lh[i] = 0;
    __syncthreads();
    for (int e = lo + t; e < hi; e += 256) atomicAdd(&lh[pairs[e] >> 16], 1);
    __syncthreads();
    if (t < 128) {
        int v = lh[t];
        int incl = v;
#pragma unroll
        for (int off = 1; off < 64; off <<= 1) {
            int y = __shfl_up(incl, off);
            if ((t & 63) >= off) incl += y;
        }
        ls[t] = incl;
    }
    __syncthreads();
    if (t < 128) {
        int v = lh[t];
        int excl = ls[t] - v + ((t >= 64) ? ls[63] : 0);
        int node = b * 128 + t;
        if (node < N) row_ptr[node] = lo + excl;
        lc[t] = excl;
    }
    __syncthreads();
    for (int e = lo + t; e < hi; e += 256) {
        unsigned int p = pairs[e];
        int ld = p >> 16;
        int idx = atomicAdd(&lc[ld], 1);
        col[lo + idx] = (unsigned short)(p & 0xFFFFu);
    }
}

// ================= agg0: wave-per-node gather-mean, 16-deep MLP =================
__global__ void agg0_kernel(const int* __restrict__ row_ptr, const unsigned short* __restrict__ col,
                            unsigned short* __restrict__ A0, int N) {
    int n = (int)((blockIdx.x * blockDim.x + threadIdx.x) >> 6);
    if (n >= N) return;
    int lane = threadIdx.x & 63;
    int rs = row_ptr[n], re = row_ptr[n + 1];
    float acc = 0.f;
    for (int base = rs; base < re; base += 64) {
        int cnt = min(64, re - base);
        int e = 0;
        if (base + lane < re) e = (int)col[base + lane];
        int j = 0;
        for (; j + 16 <= cnt; j += 16) {
            float v[16];
#pragma unroll
            for (int i = 0; i < 16; ++i) {
                int s = __shfl(e, j + i);
                v[i] = bf2f(A0[(size_t)s * 160 + lane]);
            }
#pragma unroll
            for (int i = 0; i < 16; ++i) acc += v[i];
        }
        for (; j + 4 <= cnt; j += 4) {
            float v[4];
#pragma unroll
            for (int i = 0; i < 4; ++i) {
                int s = __shfl(e, j + i);
                v[i] = bf2f(A0[(size_t)s * 160 + lane]);
            }
#pragma unroll
            for (int i = 0; i < 4; ++i) acc += v[i];
        }
        for (; j < cnt; ++j) {
            int s = __shfl(e, j);
            acc += bf2f(A0[(size_t)s * 160 + lane]);
        }
    }
    float deg = (float)(re - rs);
    float scale = 1.0f / fmaxf(deg, 1.0f);
    unsigned short* row = A0 + (size_t)n * 160;
    row[64 + lane] = f2bf(acc * scale);                 // neigh cols 64..127
    if (lane == 0) *(unsigned int*)(&row[128]) = pk2(1.0f, deg * scale);  // (1.0, degscale)
    if (lane >= 1 && lane < 16) *(unsigned int*)(&row[128 + lane * 2]) = 0u;  // pad 130..159
}

// ================= GEMM01 fused: h1 = relu(normalize(A0@B0)) in LDS, then S/Qp = h1@B1+b =================
__global__ void __launch_bounds__(256)
gemm01_kernel(const unsigned short* __restrict__ A0, const unsigned short* __restrict__ B0t,
              const unsigned short* __restrict__ B1t, const float* __restrict__ bias,
              float* __restrict__ S, float* __restrict__ Qp, int N) {
    __shared__ unsigned short As[64 * 168];    // phase 1: A-tile; phase 2: h1 tile [64][136]
    __shared__ unsigned short Bs[128 * 168];   // phase 1: B0t; phase 2: B1t [32][136]
    int t = threadIdx.x, blk = blockIdx.x;
    for (int i = t; i < 128 * 20; i += 256) {
        int r = i / 20, c = i % 20;
        *(uint4*)(&Bs[r * 168 + c * 8]) = *(const uint4*)(&B0t[r * 160 + c * 8]);
    }
    for (int i = t; i < 64 * 20; i += 256) {
        int r = i / 20, c = i % 20;
        int gr = blk * 64 + r;
        uint4 v = {0, 0, 0, 0};
        if (gr < N) v = *(const uint4*)(&A0[(size_t)gr * 160 + c * 8]);
        *(uint4*)(&As[r * 168 + c * 8]) = v;
    }
    __syncthreads();

    int wave = t >> 6, lane = t & 63;
    int lo = lane & 15, hi = lane >> 4;
    f32x4 acc[8];
#pragma unroll
    for (int f = 0; f < 8; ++f) acc[f] = (f32x4){0.f, 0.f, 0.f, 0.f};

#pragma unroll
    for (int ks = 0; ks < 5; ++ks) {
        short8 a = *(const short8*)(&As[(wave * 16 + lo) * 168 + ks * 32 + hi * 8]);
#pragma unroll
        for (int f = 0; f < 8; ++f) {
            short8 b = *(const short8*)(&Bs[(f * 16 + lo) * 168 + ks * 32 + hi * 8]);
            acc[f] = __builtin_amdgcn_mfma_f32_16x16x32_bf16(a, b, acc[f], 0, 0, 0);
        }
    }
    __syncthreads();                           // all waves done with As/Bs

    // epilogue -> h1 tile in LDS (row stride 136), relu+normalize, bf16
    unsigned short* h1s = As;                  // 64*136*2 = 17.4 KB <= As
#pragma unroll
    for (int j = 0; j < 4; ++j) {
        float s = 0.f;
#pragma unroll
        for (int f = 0; f < 8; ++f) s += acc[f][j] * acc[f][j];
#pragma unroll
        for (int m = 1; m < 16; m <<= 1) s += __shfl_xor(s, m);
        float inv = 1.0f / (sqrtf(s) + EPSN);
        int r = wave * 16 + hi * 4 + j;
#pragma unroll
        for (int f = 0; f < 8; ++f)
            h1s[r * 136 + f * 16 + lo] = f2bf(fmaxf(acc[f][j] * inv, 0.f));
    }
    // load B1t into Bs region (32 x 136, pad)
    for (int i = t; i < 32 * 16; i += 256) {
        int r = i / 16, c = i % 16;
        *(uint4*)(&Bs[r * 136 + c * 8]) = *(const uint4*)(&B1t[r * 128 + c * 8]);
    }
    __syncthreads();

    f32x4 c0 = (f32x4){0.f, 0.f, 0.f, 0.f};
    f32x4 c1 = (f32x4){0.f, 0.f, 0.f, 0.f};
#pragma unroll
    for (int ks = 0; ks < 4; ++ks) {
        short8 b0 = *(const short8*)(&Bs[lo * 136 + ks * 32 + hi * 8]);
        short8 b1 = *(const short8*)(&Bs[(16 + lo) * 136 + ks * 32 + hi * 8]);
        short8 a  = *(const short8*)(&h1s[(wave * 16 + lo) * 136 + ks * 32 + hi * 8]);
        c0 = __builtin_amdgcn_mfma_f32_16x16x32_bf16(a, b0, c0, 0, 0, 0);
        c1 = __builtin_amdgcn_mfma_f32_16x16x32_bf16(a, b1, c1, 0, 0, 0);
    }
#pragma unroll
    for (int j = 0; j < 4; ++j) {
        int gr = blk * 64 + wave * 16 + hi * 4 + j;
        if (gr < N) {
            float v0 = c0[j] + bias[lo];
            if (lo < 10) S[(size_t)gr * 10 + lo] = v0;
            else         Qp[(size_t)gr * 16 + (lo - 10)] = v0;                      // cols 0..5
            if (lo < 4)       Qp[(size_t)gr * 16 + 6 + lo] = c1[j] + bias[16 + lo]; // 6..9
            else if (lo < 10) Qp[(size_t)gr * 16 + 6 + lo] = 0.f;                   // pad 10..15
        }
    }
}

// ================= final: thread-per-node; 4-edge unroll; log_softmax =================
__global__ void final_kernel(const float* __restrict__ S, const float* __restrict__ Qp,
                             const int* __restrict__ row_ptr, const unsigned short* __restrict__ col,
                             float* __restrict__ out, int N) {
    int n = blockIdx.x * blockDim.x + threadIdx.x;
    if (n >= N) return;
    int rs = row_ptr[n], re = row_ptr[n + 1];
    float q0 = 0.f, q1 = 0.f, q2 = 0.f, q3 = 0.f, q4 = 0.f;
    float q5 = 0.f, q6 = 0.f, q7 = 0.f, q8 = 0.f, q9 = 0.f;
    int e = rs;
    for (; e + 3 < re; e += 4) {
        float4 a[4], b[4]; float2 t2[4];
#pragma unroll
        for (int i = 0; i < 4; ++i) {
            int c = (int)col[e + i];
            const float4* r = (const float4*)(&Qp[(size_t)c * 16]);
            a[i] = r[0]; b[i] = r[1];
            t2[i] = *(const float2*)(&Qp[(size_t)c * 16 + 8]);
        }
#pragma unroll
        for (int i = 0; i < 4; ++i) {
            q0 += a[i].x; q1 += a[i].y; q2 += a[i].z; q3 += a[i].w;
            q4 += b[i].x; q5 += b[i].y; q6 += b[i].z; q7 += b[i].w;
            q8 += t2[i].x; q9 += t2[i].y;
        }
    }
    for (; e < re; ++e) {
        int c0 = (int)col[e];
        const float4* r0 = (const float4*)(&Qp[(size_t)c0 * 16]);
        float4 a0 = r0[0], b0 = r0[1];
        float2 t0 = *(const float2*)(&Qp[(size_t)c0 * 16 + 8]);
        q0 += a0.x; q1 += a0.y; q2 += a0.z; q3 += a0.w;
        q4 += b0.x; q5 += b0.y; q6 += b0.z; q7 += b0.w;
        q8 += t0.x; q9 += t0.y;
    }
    float deg = (float)(re - rs);
    float scale = 1.0f / fmaxf(deg, 1.0f);
    const float* Sr = &S[(size_t)n * 10];
    float p[10];
    p[0] = Sr[0] + q0 * scale; p[1] = Sr[1] + q1 * scale;
    p[2] = Sr[2] + q2 * scale; p[3] = Sr[3] + q3 * scale;
    p[4] = Sr[4] + q4 * scale; p[5] = Sr[5] + q5 * scale;
    p[6] = Sr[6] + q6 * scale; p[7] = Sr[7] + q7 * scale;
    p[8] = Sr[8] + q8 * scale; p[9] = Sr[9] + q9 * scale;
    float ss = 0.f;
#pragma unroll
    for (int j = 0; j < 10; ++j) ss = fmaf(p[j], p[j], ss);
    float inv = 1.0f / (sqrtf(ss) + EPSN);
    float m = -INFINITY;
#pragma unroll
    for (int j = 0; j < 10; ++j) { p[j] *= inv; m = fmaxf(m, p[j]); }
    float se = 0.f;
#pragma unroll
    for (int j = 0; j < 10; ++j) se += expf(p[j] - m);
    float ls = logf(se) + m;
#pragma unroll
    for (int j = 0; j < 10; ++j) out[(size_t)n * 10 + j] = p[j] - ls;
}

extern "C" void kernel_launch(void* const* d_in, const int* in_sizes, int n_in,
                              void* d_out, int out_size, void* d_ws, size_t ws_size,
                              hipStream_t stream) {
    const float* x   = (const float*)d_in[0];
    const int*   ei  = (const int*)d_in[1];
    const float* Ws0 = (const float*)d_in[2];
    const float* Wn0 = (const float*)d_in[3];
    const float* Ws1 = (const float*)d_in[4];
    const float* Wn1 = (const float*)d_in[5];

    int N = in_sizes[0] / 64;
    int E = in_sizes[1] / 2;
    const int* src = ei;
    const int* dst = ei + E;
    int nbuck = (N + 127) / 128;

    char* ws = (char*)d_ws;
    size_t off = 0;
    unsigned short* A0   = (unsigned short*)(ws + off); off += (size_t)N * 160 * 2;
    float*          S    = (float*)(ws + off);          off += (size_t)N * 10 * 4;
    float*          Qp   = (float*)(ws + off);          off += (size_t)N * 16 * 4;
    unsigned short* B0t  = (unsigned short*)(ws + off); off += 128 * 160 * 2;
    unsigned short* B1t  = (unsigned short*)(ws + off); off += 32 * 128 * 2;
    float*          bias = (float*)(ws + off);          off += 128;
    int*            rowp = (int*)(ws + off);            off += ((size_t)N + 4) * 4;
    unsigned short* colb = (unsigned short*)(ws + off); off += ((size_t)E + 8) * 2;
    unsigned int*   pairs= (unsigned int*)(ws + off);   off += (size_t)E * 4;
    int*            ghist= (int*)(ws + off);            off += MAXBUCK * 4;
    int*            phist= (int*)(ws + off);            off += (size_t)HISTB * MAXBUCK * 4;
    int*            boff = (int*)(ws + off);            off += (MAXBUCK + 1) * 4;
    int*            bcur = (int*)(ws + off);            off += MAXBUCK * 4;
    float* outp = (float*)d_out;

    int prepB = (128 * 160 + 32 * 128 + 20 + 255) / 256;
    int xcvB  = (N * 8 + 255) / 256;

    hipMemsetAsync(ghist, 0, MAXBUCK * 4, stream);
    fused_pre<<<HISTB + prepB + xcvB, 256, 0, stream>>>(
        dst, ghist, phist, E, nbuck, Ws0, Wn0, Ws1, Wn1, B0t, B1t, bias, x, A0, N, prepB);
    bucket_scan   <<<1, MAXBUCK, 0, stream>>>(ghist, boff, bcur, nbuck, E, rowp, N);
    bucket_scatter<<<HISTB, 256, 0, stream>>>(src, dst, phist, bcur, pairs, E);
    csr_finalize  <<<nbuck, 256, 0, stream>>>(pairs, boff, rowp, colb, N);

    agg0_kernel <<<(N + 3) / 4, 256, 0, stream>>>(rowp, colb, A0, N);
    gemm01_kernel<<<(N + 63) / 64, 256, 0, stream>>>(A0, B0t, B1t, bias, S, Qp, N);
    final_kernel<<<(N + 255) / 256, 256, 0, stream>>>(S, Qp, rowp, colb, outp, N);
}

// Round 15
// 177.224 us; speedup vs baseline: 1.9331x; 1.0646x over previous
//
#include <hip/hip_runtime.h>
#include <hip/hip_bf16.h>
#include <math.h>

#define EPSN 1e-8f
#define MAXBUCK 512          // buckets of 128 nodes; requires N < 65536 (ushort col)
#define HISTB 256            // hist/scatter grid (matched; 256 keeps pairs run-length at 24B)

typedef __attribute__((ext_vector_type(8))) short short8;
typedef __attribute__((ext_vector_type(4))) float f32x4;

static __device__ __forceinline__ unsigned short f2bf(float f) {
    union { float f; unsigned int u; } v; v.f = f;
    unsigned int u = v.u;
    return (unsigned short)((u + 0x7fffu + ((u >> 16) & 1u)) >> 16);  // RNE
}
static __device__ __forceinline__ float bf2f(unsigned short h) {
    union { unsigned int u; float f; } v; v.u = ((unsigned int)h) << 16;
    return v.f;
}
static __device__ __forceinline__ unsigned int pk2(float a, float b) {
    return (((unsigned int)f2bf(b)) << 16) | (unsigned int)f2bf(a);
}

// ================= fused pre: bucket hist (-> ghist + phist) | weight prep | x->bf16 =================
__global__ void fused_pre(const int* __restrict__ dst, int* __restrict__ ghist,
                          int* __restrict__ phist, int E, int nbuck,
                          const float* __restrict__ Ws0, const float* __restrict__ Wn0,
                          const float* __restrict__ Ws1, const float* __restrict__ Wn1,
                          unsigned short* __restrict__ B0t, unsigned short* __restrict__ B1t,
                          float* __restrict__ bias,
                          const float* __restrict__ x, unsigned short* __restrict__ A0, int N,
                          int prepB) {
    int b = blockIdx.x;
    if (b < HISTB) {
        __shared__ int h[MAXBUCK];
        for (int i = threadIdx.x; i < MAXBUCK; i += 256) h[i] = 0;
        __syncthreads();
        int CH = (E + HISTB - 1) / HISTB;
        int lo = b * CH, hi = min(E, lo + CH);
        for (int e = lo + (int)threadIdx.x; e < hi; e += 256) atomicAdd(&h[dst[e] >> 7], 1);
        __syncthreads();
        for (int i = threadIdx.x; i < MAXBUCK; i += 256) {
            int c = h[i];
            phist[b * MAXBUCK + i] = c;                  // per-block counts for scatter
            if (c && i < nbuck) atomicAdd(&ghist[i], c);
        }
        return;
    }
    if (b < HISTB + prepB) {
        int t = (b - HISTB) * 256 + threadIdx.x;
        if (t < 128 * 160) {
            int n = t / 160, k = t % 160;
            float v = 0.f;
            if (k < 64) v = Ws0[k * 128 + n];
            else if (k < 128) v = Wn0[(k - 64) * 128 + n];
            else if (k == 128) v = Ws0[64 * 128 + n];
            else if (k == 129) v = Wn0[64 * 128 + n];
            B0t[n * 160 + k] = f2bf(v);
        }
        int u = t - 128 * 160;
        if (u >= 0 && u < 32 * 128) {
            int c = u / 128, k = u % 128;
            float v = 0.f;
            if (c < 10) v = Ws1[k * 10 + c];
            else if (c < 20) v = Wn1[k * 10 + (c - 10)];
            B1t[c * 128 + k] = f2bf(v);
        }
        int w = t - 128 * 160 - 32 * 128;
        if (w >= 0 && w < 20) bias[w] = (w < 10) ? Ws1[128 * 10 + w] : Wn1[128 * 10 + (w - 10)];
        return;
    }
    int u = (b - HISTB - prepB) * 256 + threadIdx.x;   // u = n*8 + s
    if (u >= N * 8) return;
    int n = u >> 3, s = u & 7;
    const float4* xp = (const float4*)(x + (size_t)n * 64 + s * 8);
    float4 v0 = xp[0], v1 = xp[1];
    short8 r;
    r[0] = (short)f2bf(v0.x); r[1] = (short)f2bf(v0.y);
    r[2] = (short)f2bf(v0.z); r[3] = (short)f2bf(v0.w);
    r[4] = (short)f2bf(v1.x); r[5] = (short)f2bf(v1.y);
    r[6] = (short)f2bf(v1.z); r[7] = (short)f2bf(v1.w);
    *(short8*)(&A0[(size_t)n * 160 + s * 8]) = r;
}

// ================= bucket scan (1 block) =================
__global__ void bucket_scan(const int* __restrict__ ghist, int* __restrict__ boff,
                            int* __restrict__ bcur, int nbuck, int E,
                            int* __restrict__ row_ptr, int N) {
    __shared__ int bufa[MAXBUCK], bufb[MAXBUCK];
    int t = threadIdx.x;  // MAXBUCK threads
    int v = (t < nbuck) ? ghist[t] : 0;
    bufa[t] = v;
    __syncthreads();
    int* cur = bufa; int* nxt = bufb;
    for (int off = 1; off < MAXBUCK; off <<= 1) {
        int xv = cur[t];
        if (t >= off) xv += cur[t - off];
        nxt[t] = xv;
        __syncthreads();
        int* tmp = cur; cur = nxt; nxt = tmp;
    }
    int incl = cur[t];
    int excl = incl - v;
    if (t < nbuck) { boff[t] = excl; bcur[t] = excl; }
    if (t == nbuck - 1) boff[nbuck] = incl;   // == E
    if (t == 0) row_ptr[N] = E;
}

// ================= binned scatter (uses precomputed per-block hist; single dst pass) =================
__global__ void bucket_scatter(const int* __restrict__ src, const int* __restrict__ dst,
                               const int* __restrict__ phist,
                               int* __restrict__ bcur, unsigned int* __restrict__ pairs,
                               int E) {
    __shared__ int h[MAXBUCK];
    __shared__ int bs[MAXBUCK];
    int b = blockIdx.x;
    for (int i = threadIdx.x; i < MAXBUCK; i += 256) {
        int c = phist[b * MAXBUCK + i];
        bs[i] = c ? atomicAdd(&bcur[i], c) : 0;
        h[i] = 0;
    }
    __syncthreads();
    int CH = (E + HISTB - 1) / HISTB;
    int lo = b * CH, hi = min(E, lo + CH);
    for (int e = lo + (int)threadIdx.x; e < hi; e += 256) {
        int d = dst[e];
        int bkt = d >> 7;
        int idx = atomicAdd(&h[bkt], 1);
        pairs[bs[bkt] + idx] = (((unsigned int)(d & 127)) << 16) | (unsigned int)src[e];
    }
}

// ================= per-bucket finalize -> row_ptr + ushort col =================
__global__ void csr_finalize(const unsigned int* __restrict__ pairs, const int* __restrict__ boff,
                             int* __restrict__ row_ptr, unsigned short* __restrict__ col,
                             int N) {
    __shared__ int lh[128], ls[128], lc[128];
    int b = blockIdx.x, t = threadIdx.x;  // 256 threads
    int lo = boff[b], hi = boff[b + 1];
    for (int i = t; i < 128; i += 256) lh[i] = 0;
    __syncthreads();
    for (int e = lo + t; e < hi; e += 256) atomicAdd(&lh[pairs[e] >> 16], 1);
    __syncthreads();
    if (t < 128) {
        int v = lh[t];
        int incl = v;
#pragma unroll
        for (int off = 1; off < 64; off <<= 1) {
            int y = __shfl_up(incl, off);
            if ((t & 63) >= off) incl += y;
        }
        ls[t] = incl;
    }
    __syncthreads();
    if (t < 128) {
        int v = lh[t];
        int excl = ls[t] - v + ((t >= 64) ? ls[63] : 0);
        int node = b * 128 + t;
        if (node < N) row_ptr[node] = lo + excl;
        lc[t] = excl;
    }
    __syncthreads();
    for (int e = lo + t; e < hi; e += 256) {
        unsigned int p = pairs[e];
        int ld = p >> 16;
        int idx = atomicAdd(&lc[ld], 1);
        col[lo + idx] = (unsigned short)(p & 0xFFFFu);
    }
}

// ================= agg0: wave-per-node gather-mean, 16-deep MLP =================
__global__ void agg0_kernel(const int* __restrict__ row_ptr, const unsigned short* __restrict__ col,
                            unsigned short* __restrict__ A0, int N) {
    int n = (int)((blockIdx.x * blockDim.x + threadIdx.x) >> 6);
    if (n >= N) return;
    int lane = threadIdx.x & 63;
    int rs = row_ptr[n], re = row_ptr[n + 1];
    float acc = 0.f;
    for (int base = rs; base < re; base += 64) {
        int cnt = min(64, re - base);
        int e = 0;
        if (base + lane < re) e = (int)col[base + lane];
        int j = 0;
        for (; j + 16 <= cnt; j += 16) {
            float v[16];
#pragma unroll
            for (int i = 0; i < 16; ++i) {
                int s = __shfl(e, j + i);
                v[i] = bf2f(A0[(size_t)s * 160 + lane]);
            }
#pragma unroll
            for (int i = 0; i < 16; ++i) acc += v[i];
        }
        for (; j + 4 <= cnt; j += 4) {
            float v[4];
#pragma unroll
            for (int i = 0; i < 4; ++i) {
                int s = __shfl(e, j + i);
                v[i] = bf2f(A0[(size_t)s * 160 + lane]);
            }
#pragma unroll
            for (int i = 0; i < 4; ++i) acc += v[i];
        }
        for (; j < cnt; ++j) {
            int s = __shfl(e, j);
            acc += bf2f(A0[(size_t)s * 160 + lane]);
        }
    }
    float deg = (float)(re - rs);
    float scale = 1.0f / fmaxf(deg, 1.0f);
    unsigned short* row = A0 + (size_t)n * 160;
    row[64 + lane] = f2bf(acc * scale);                 // neigh cols 64..127
    if (lane == 0) *(unsigned int*)(&row[128]) = pk2(1.0f, deg * scale);  // (1.0, degscale)
    if (lane >= 1 && lane < 16) *(unsigned int*)(&row[128 + lane * 2]) = 0u;  // pad 130..159
}

// ================= GEMM0: h1 = relu(normalize(A0 @ B0)) =================
__global__ void __launch_bounds__(256)
gemm0_kernel(const unsigned short* __restrict__ A0, const unsigned short* __restrict__ B0t,
             unsigned short* __restrict__ h1, int N) {
    __shared__ unsigned short As[64 * 168];
    __shared__ unsigned short Bs[128 * 168];
    int t = threadIdx.x, blk = blockIdx.x;
    for (int i = t; i < 128 * 20; i += 256) {
        int r = i / 20, c = i % 20;
        *(uint4*)(&Bs[r * 168 + c * 8]) = *(const uint4*)(&B0t[r * 160 + c * 8]);
    }
    for (int i = t; i < 64 * 20; i += 256) {
        int r = i / 20, c = i % 20;
        int gr = blk * 64 + r;
        uint4 v = {0, 0, 0, 0};
        if (gr < N) v = *(const uint4*)(&A0[(size_t)gr * 160 + c * 8]);
        *(uint4*)(&As[r * 168 + c * 8]) = v;
    }
    __syncthreads();

    int wave = t >> 6, lane = t & 63;
    int lo = lane & 15, hi = lane >> 4;
    f32x4 acc[8];
#pragma unroll
    for (int f = 0; f < 8; ++f) acc[f] = (f32x4){0.f, 0.f, 0.f, 0.f};

#pragma unroll
    for (int ks = 0; ks < 5; ++ks) {
        short8 a = *(const short8*)(&As[(wave * 16 + lo) * 168 + ks * 32 + hi * 8]);
#pragma unroll
        for (int f = 0; f < 8; ++f) {
            short8 b = *(const short8*)(&Bs[(f * 16 + lo) * 168 + ks * 32 + hi * 8]);
            acc[f] = __builtin_amdgcn_mfma_f32_16x16x32_bf16(a, b, acc[f], 0, 0, 0);
        }
    }
#pragma unroll
    for (int j = 0; j < 4; ++j) {
        float s = 0.f;
#pragma unroll
        for (int f = 0; f < 8; ++f) s += acc[f][j] * acc[f][j];
#pragma unroll
        for (int m = 1; m < 16; m <<= 1) s += __shfl_xor(s, m);
        float inv = 1.0f / (sqrtf(s) + EPSN);
        int gr = blk * 64 + wave * 16 + hi * 4 + j;
        if (gr < N) {
#pragma unroll
            for (int f = 0; f < 8; ++f)
                h1[(size_t)gr * 128 + f * 16 + lo] = f2bf(fmaxf(acc[f][j] * inv, 0.f));
        }
    }
}

// ================= GEMM1: S[N][10] = h1@Ws1+b ; Qp[N][16] = [h1@Wn1+b | 0 pad] =================
__global__ void __launch_bounds__(256)
gemm1_kernel(const unsigned short* __restrict__ h1, const unsigned short* __restrict__ B1t,
             const float* __restrict__ bias, float* __restrict__ S, float* __restrict__ Qp, int N) {
    __shared__ unsigned short As[128 * 136];
    __shared__ unsigned short Bs[32 * 136];
    int t = threadIdx.x, blk = blockIdx.x;
    for (int i = t; i < 32 * 16; i += 256) {
        int r = i / 16, c = i % 16;
        *(uint4*)(&Bs[r * 136 + c * 8]) = *(const uint4*)(&B1t[r * 128 + c * 8]);
    }
    for (int i = t; i < 128 * 16; i += 256) {
        int r = i / 16, c = i % 16;
        int gr = blk * 128 + r;
        uint4 v = {0, 0, 0, 0};
        if (gr < N) v = *(const uint4*)(&h1[(size_t)gr * 128 + c * 8]);
        *(uint4*)(&As[r * 136 + c * 8]) = v;
    }
    __syncthreads();

    int wave = t >> 6, lane = t & 63, lo = lane & 15, hi = lane >> 4;
    f32x4 acc[2][2];
#pragma unroll
    for (int m = 0; m < 2; ++m) { acc[m][0] = (f32x4){0,0,0,0}; acc[m][1] = (f32x4){0,0,0,0}; }

#pragma unroll
    for (int ks = 0; ks < 4; ++ks) {
        short8 b0 = *(const short8*)(&Bs[lo * 136 + ks * 32 + hi * 8]);
        short8 b1 = *(const short8*)(&Bs[(16 + lo) * 136 + ks * 32 + hi * 8]);
#pragma unroll
        for (int m = 0; m < 2; ++m) {
            short8 a = *(const short8*)(&As[(wave * 32 + m * 16 + lo) * 136 + ks * 32 + hi * 8]);
            acc[m][0] = __builtin_amdgcn_mfma_f32_16x16x32_bf16(a, b0, acc[m][0], 0, 0, 0);
            acc[m][1] = __builtin_amdgcn_mfma_f32_16x16x32_bf16(a, b1, acc[m][1], 0, 0, 0);
        }
    }
#pragma unroll
    for (int m = 0; m < 2; ++m)
#pragma unroll
        for (int j = 0; j < 4; ++j) {
            int gr = blk * 128 + wave * 32 + m * 16 + hi * 4 + j;
            if (gr < N) {
                float v0 = acc[m][0][j] + bias[lo];
                if (lo < 10) S[(size_t)gr * 10 + lo] = v0;
                else         Qp[(size_t)gr * 16 + (lo - 10)] = v0;                          // cols 0..5
                if (lo < 4)       Qp[(size_t)gr * 16 + 6 + lo] = acc[m][1][j] + bias[16 + lo]; // 6..9
                else if (lo < 10) Qp[(size_t)gr * 16 + 6 + lo] = 0.f;                       // pad 10..15
            }
        }
}

// ================= final: thread-per-node; 4-edge unroll; log_softmax =================
__global__ void final_kernel(const float* __restrict__ S, const float* __restrict__ Qp,
                             const int* __restrict__ row_ptr, const unsigned short* __restrict__ col,
                             float* __restrict__ out, int N) {
    int n = blockIdx.x * blockDim.x + threadIdx.x;
    if (n >= N) return;
    int rs = row_ptr[n], re = row_ptr[n + 1];
    float q0 = 0.f, q1 = 0.f, q2 = 0.f, q3 = 0.f, q4 = 0.f;
    float q5 = 0.f, q6 = 0.f, q7 = 0.f, q8 = 0.f, q9 = 0.f;
    int e = rs;
    for (; e + 3 < re; e += 4) {
        float4 a[4], b[4]; float2 t2[4];
#pragma unroll
        for (int i = 0; i < 4; ++i) {
            int c = (int)col[e + i];
            const float4* r = (const float4*)(&Qp[(size_t)c * 16]);
            a[i] = r[0]; b[i] = r[1];
            t2[i] = *(const float2*)(&Qp[(size_t)c * 16 + 8]);
        }
#pragma unroll
        for (int i = 0; i < 4; ++i) {
            q0 += a[i].x; q1 += a[i].y; q2 += a[i].z; q3 += a[i].w;
            q4 += b[i].x; q5 += b[i].y; q6 += b[i].z; q7 += b[i].w;
            q8 += t2[i].x; q9 += t2[i].y;
        }
    }
    for (; e < re; ++e) {
        int c0 = (int)col[e];
        const float4* r0 = (const float4*)(&Qp[(size_t)c0 * 16]);
        float4 a0 = r0[0], b0 = r0[1];
        float2 t0 = *(const float2*)(&Qp[(size_t)c0 * 16 + 8]);
        q0 += a0.x; q1 += a0.y; q2 += a0.z; q3 += a0.w;
        q4 += b0.x; q5 += b0.y; q6 += b0.z; q7 += b0.w;
        q8 += t0.x; q9 += t0.y;
    }
    float deg = (float)(re - rs);
    float scale = 1.0f / fmaxf(deg, 1.0f);
    const float* Sr = &S[(size_t)n * 10];
    float p[10];
    p[0] = Sr[0] + q0 * scale; p[1] = Sr[1] + q1 * scale;
    p[2] = Sr[2] + q2 * scale; p[3] = Sr[3] + q3 * scale;
    p[4] = Sr[4] + q4 * scale; p[5] = Sr[5] + q5 * scale;
    p[6] = Sr[6] + q6 * scale; p[7] = Sr[7] + q7 * scale;
    p[8] = Sr[8] + q8 * scale; p[9] = Sr[9] + q9 * scale;
    float ss = 0.f;
#pragma unroll
    for (int j = 0; j < 10; ++j) ss = fmaf(p[j], p[j], ss);
    float inv = 1.0f / (sqrtf(ss) + EPSN);
    float m = -INFINITY;
#pragma unroll
    for (int j = 0; j < 10; ++j) { p[j] *= inv; m = fmaxf(m, p[j]); }
    float se = 0.f;
#pragma unroll
    for (int j = 0; j < 10; ++j) se += expf(p[j] - m);
    float ls = logf(se) + m;
#pragma unroll
    for (int j = 0; j < 10; ++j) out[(size_t)n * 10 + j] = p[j] - ls;
}

extern "C" void kernel_launch(void* const* d_in, const int* in_sizes, int n_in,
                              void* d_out, int out_size, void* d_ws, size_t ws_size,
                              hipStream_t stream) {
    const float* x   = (const float*)d_in[0];
    const int*   ei  = (const int*)d_in[1];
    const float* Ws0 = (const float*)d_in[2];
    const float* Wn0 = (const float*)d_in[3];
    const float* Ws1 = (const float*)d_in[4];
    const float* Wn1 = (const float*)d_in[5];

    int N = in_sizes[0] / 64;
    int E = in_sizes[1] / 2;
    const int* src = ei;
    const int* dst = ei + E;
    int nbuck = (N + 127) / 128;

    char* ws = (char*)d_ws;
    size_t off = 0;
    unsigned short* A0   = (unsigned short*)(ws + off); off += (size_t)N * 160 * 2;
    unsigned short* h1   = (unsigned short*)(ws + off); off += (size_t)N * 128 * 2;
    float*          S    = (float*)(ws + off);          off += (size_t)N * 10 * 4;
    float*          Qp   = (float*)(ws + off);          off += (size_t)N * 16 * 4;
    unsigned short* B0t  = (unsigned short*)(ws + off); off += 128 * 160 * 2;
    unsigned short* B1t  = (unsigned short*)(ws + off); off += 32 * 128 * 2;
    float*          bias = (float*)(ws + off);          off += 128;
    int*            rowp = (int*)(ws + off);            off += ((size_t)N + 4) * 4;
    unsigned short* colb = (unsigned short*)(ws + off); off += ((size_t)E + 8) * 2;
    unsigned int*   pairs= (unsigned int*)(ws + off);   off += (size_t)E * 4;
    int*            ghist= (int*)(ws + off);            off += MAXBUCK * 4;
    int*            phist= (int*)(ws + off);            off += (size_t)HISTB * MAXBUCK * 4;
    int*            boff = (int*)(ws + off);            off += (MAXBUCK + 1) * 4;
    int*            bcur = (int*)(ws + off);            off += MAXBUCK * 4;
    float* outp = (float*)d_out;

    int prepB = (128 * 160 + 32 * 128 + 20 + 255) / 256;
    int xcvB  = (N * 8 + 255) / 256;

    hipMemsetAsync(ghist, 0, MAXBUCK * 4, stream);
    fused_pre<<<HISTB + prepB + xcvB, 256, 0, stream>>>(
        dst, ghist, phist, E, nbuck, Ws0, Wn0, Ws1, Wn1, B0t, B1t, bias, x, A0, N, prepB);
    bucket_scan   <<<1, MAXBUCK, 0, stream>>>(ghist, boff, bcur, nbuck, E, rowp, N);
    bucket_scatter<<<HISTB, 256, 0, stream>>>(src, dst, phist, bcur, pairs, E);
    csr_finalize  <<<nbuck, 256, 0, stream>>>(pairs, boff, rowp, colb, N);

    agg0_kernel <<<(N + 3) / 4, 256, 0, stream>>>(rowp, colb, A0, N);
    gemm0_kernel<<<(N + 63) / 64, 256, 0, stream>>>(A0, B0t, h1, N);
    gemm1_kernel<<<(N + 127) / 128, 256, 0, stream>>>(h1, B1t, bias, S, Qp, N);
    final_kernel<<<(N + 255) / 256, 256, 0, stream>>>(S, Qp, rowp, colb, outp, N);
}